// Round 1
// baseline (942.828 us; speedup 1.0000x reference)
//
#include <hip/hip_runtime.h>

#define BN_EPS 1e-4f

// ---------------------------------------------------------------------------
// wave-wide (64-lane) butterfly sum
__device__ __forceinline__ float wred(float v) {
#pragma unroll
    for (int off = 32; off > 0; off >>= 1) v += __shfl_xor(v, off);
    return v;
}

// ---------------------------------------------------------------------------
// Rulebook gather-conv: out[n, 0:16] = sum_k act[nbr[k,n], 0:CIN] @ W[k]
// - thread = one output site, 16 fp32 accumulators in VGPRs
// - sentinel (idx == Nin) taps skipped (rulebook is mostly sentinel at L0)
// - W indexed wave-uniformly -> scalar loads, v_fma with SGPR operand
// - optional fused skip add (out += conv) and fused BN-stat accumulation
//   (sum at stats[c], sum-of-squares at stats[64+c])
template <int K, int CIN>
__global__ __launch_bounds__(256) void sconv_k(
    const float* __restrict__ act,   // [Nin, CIN]
    const int* __restrict__ nbr,     // [K, Nout], sentinel == Nin
    const float* __restrict__ W,     // [K, CIN, 16]
    float* __restrict__ out,         // [Nout, 16]
    float* __restrict__ stats,       // [128] (sum | sumsq at +64) or nullptr
    int Nout, int Nin, int addSkip)
{
    const int n = blockIdx.x * 256 + threadIdx.x;
    const bool valid = (n < Nout);

    float acc[16];
#pragma unroll
    for (int c = 0; c < 16; ++c) acc[c] = 0.f;

    if (valid) {
#pragma unroll 1
        for (int k = 0; k < K; ++k) {
            const int idx = nbr[(size_t)k * Nout + n];
            if (idx < Nin) {
                const float* __restrict__ Wk = W + k * (CIN * 16);
                if constexpr (CIN == 16) {
                    const float4* ar = (const float4*)(act + (size_t)idx * 16);
                    const float4 r0 = ar[0], r1 = ar[1], r2 = ar[2], r3 = ar[3];
                    float a[16];
                    a[0] = r0.x; a[1] = r0.y; a[2] = r0.z; a[3] = r0.w;
                    a[4] = r1.x; a[5] = r1.y; a[6] = r1.z; a[7] = r1.w;
                    a[8] = r2.x; a[9] = r2.y; a[10] = r2.z; a[11] = r2.w;
                    a[12] = r3.x; a[13] = r3.y; a[14] = r3.z; a[15] = r3.w;
#pragma unroll
                    for (int ci = 0; ci < 16; ++ci) {
                        const float av = a[ci];
#pragma unroll
                        for (int co = 0; co < 16; ++co)
                            acc[co] = fmaf(av, Wk[ci * 16 + co], acc[co]);
                    }
                } else {  // CIN == 2 (p1 conv from raw feats)
                    const float2 r = *(const float2*)(act + (size_t)idx * 2);
#pragma unroll
                    for (int co = 0; co < 16; ++co)
                        acc[co] = fmaf(r.x, Wk[co], acc[co]);
#pragma unroll
                    for (int co = 0; co < 16; ++co)
                        acc[co] = fmaf(r.y, Wk[16 + co], acc[co]);
                }
            }
        }
        if (addSkip) {
            const float4* so = (const float4*)(out + (size_t)n * 16);
            const float4 s0 = so[0], s1 = so[1], s2 = so[2], s3 = so[3];
            acc[0] += s0.x; acc[1] += s0.y; acc[2] += s0.z; acc[3] += s0.w;
            acc[4] += s1.x; acc[5] += s1.y; acc[6] += s1.z; acc[7] += s1.w;
            acc[8] += s2.x; acc[9] += s2.y; acc[10] += s2.z; acc[11] += s2.w;
            acc[12] += s3.x; acc[13] += s3.y; acc[14] += s3.z; acc[15] += s3.w;
        }
        float4* o = (float4*)(out + (size_t)n * 16);
        o[0] = make_float4(acc[0], acc[1], acc[2], acc[3]);
        o[1] = make_float4(acc[4], acc[5], acc[6], acc[7]);
        o[2] = make_float4(acc[8], acc[9], acc[10], acc[11]);
        o[3] = make_float4(acc[12], acc[13], acc[14], acc[15]);
    }

    if (stats) {  // uniform branch (kernel arg)
        __shared__ float red[4][32];
        const int wave = threadIdx.x >> 6, lane = threadIdx.x & 63;
#pragma unroll
        for (int c = 0; c < 16; ++c) {
            const float v = valid ? acc[c] : 0.f;
            const float ss = wred(v);
            const float qq = wred(v * v);
            if (lane == 0) { red[wave][c] = ss; red[wave][16 + c] = qq; }
        }
        __syncthreads();
        if (threadIdx.x < 32) {
            const int t = threadIdx.x;
            const float v = red[0][t] + red[1][t] + red[2][t] + red[3][t];
            atomicAdd(stats + (t < 16 ? t : 48 + t), v);  // sumsq at 64 + (t-16)
        }
    }
}

// ---------------------------------------------------------------------------
// BN finalize: scale/bias from accumulated stats; zeroes stats for next use.
__global__ void fin_k(float* __restrict__ stats, const float* __restrict__ g,
                      const float* __restrict__ b, float* __restrict__ sb,
                      int C, float invN)
{
    const int c = threadIdx.x;  // launched with 64 threads
    if (c < C) {
        const float mean = stats[c] * invN;
        const float var = stats[64 + c] * invN - mean * mean;
        const float sc = g[c] * rsqrtf(var + BN_EPS);
        sb[c] = sc;
        sb[64 + c] = fmaf(-mean, sc, b[c]);
    }
    stats[c] = 0.f;
    stats[64 + c] = 0.f;
}

// ---------------------------------------------------------------------------
// BN + ReLU apply: A = relu(x * scale + bias), vectorized float4 (4 ch/thread)
__global__ __launch_bounds__(256) void apply_k(const float* __restrict__ x,
                                               const float* __restrict__ sb,
                                               float* __restrict__ A, int N)
{
    const int t = blockIdx.x * 256 + threadIdx.x;
    if (t < N * 4) {
        const int c = (t & 3) << 2;
        const float4 v = ((const float4*)x)[t];
        float4 r;
        r.x = fmaxf(fmaf(v.x, sb[c + 0], sb[64 + c + 0]), 0.f);
        r.y = fmaxf(fmaf(v.y, sb[c + 1], sb[64 + c + 1]), 0.f);
        r.z = fmaxf(fmaf(v.z, sb[c + 2], sb[64 + c + 2]), 0.f);
        r.w = fmaxf(fmaf(v.w, sb[c + 3], sb[64 + c + 3]), 0.f);
        ((float4*)A)[t] = r;
    }
}

// ---------------------------------------------------------------------------
// Stats of the gathered concat [r0 | r1[p01] | r2[p12[p01]]] over N0 rows.
__global__ __launch_bounds__(256) void gstats_k(
    const float* __restrict__ R0, const float* __restrict__ R1,
    const float* __restrict__ R2, const int* __restrict__ p01,
    const int* __restrict__ p12, float* __restrict__ stats, int N0)
{
    float s[48], q[48];
#pragma unroll
    for (int c = 0; c < 48; ++c) { s[c] = 0.f; q[c] = 0.f; }

    for (int n = blockIdx.x * blockDim.x + threadIdx.x; n < N0;
         n += gridDim.x * blockDim.x) {
        const int i1 = p01[n];
        const int i2 = p12[i1];
        const float4* a0 = (const float4*)(R0 + (size_t)n * 16);
        const float4* a1 = (const float4*)(R1 + (size_t)i1 * 16);
        const float4* a2 = (const float4*)(R2 + (size_t)i2 * 16);
#pragma unroll
        for (int j = 0; j < 4; ++j) {
            const float4 v = a0[j]; const int c = 4 * j;
            s[c] += v.x; q[c] += v.x * v.x; s[c+1] += v.y; q[c+1] += v.y * v.y;
            s[c+2] += v.z; q[c+2] += v.z * v.z; s[c+3] += v.w; q[c+3] += v.w * v.w;
        }
#pragma unroll
        for (int j = 0; j < 4; ++j) {
            const float4 v = a1[j]; const int c = 16 + 4 * j;
            s[c] += v.x; q[c] += v.x * v.x; s[c+1] += v.y; q[c+1] += v.y * v.y;
            s[c+2] += v.z; q[c+2] += v.z * v.z; s[c+3] += v.w; q[c+3] += v.w * v.w;
        }
#pragma unroll
        for (int j = 0; j < 4; ++j) {
            const float4 v = a2[j]; const int c = 32 + 4 * j;
            s[c] += v.x; q[c] += v.x * v.x; s[c+1] += v.y; q[c+1] += v.y * v.y;
            s[c+2] += v.z; q[c+2] += v.z * v.z; s[c+3] += v.w; q[c+3] += v.w * v.w;
        }
    }

    __shared__ float red[4][96];
    const int wave = threadIdx.x >> 6, lane = threadIdx.x & 63;
#pragma unroll
    for (int c = 0; c < 48; ++c) {
        const float ss = wred(s[c]);
        const float qq = wred(q[c]);
        if (lane == 0) { red[wave][c] = ss; red[wave][48 + c] = qq; }
    }
    __syncthreads();
    const int t = threadIdx.x;
    if (t < 96) {
        const float v = red[0][t] + red[1][t] + red[2][t] + red[3][t];
        atomicAdd(stats + (t < 48 ? t : 64 + (t - 48)), v);
    }
}

// ---------------------------------------------------------------------------
// Final: out[n] = relu(bn48(concat)) . w_sdf + b_sdf
__global__ __launch_bounds__(256) void out_k(
    const float* __restrict__ R0, const float* __restrict__ R1,
    const float* __restrict__ R2, const int* __restrict__ p01,
    const int* __restrict__ p12, const float* __restrict__ sb,
    const float* __restrict__ wsdf, const float* __restrict__ bsdf,
    float* __restrict__ out, int N0)
{
    const int n = blockIdx.x * 256 + threadIdx.x;
    if (n >= N0) return;
    const int i1 = p01[n];
    const int i2 = p12[i1];
    float acc = bsdf[0];
    const float4* a0 = (const float4*)(R0 + (size_t)n * 16);
    const float4* a1 = (const float4*)(R1 + (size_t)i1 * 16);
    const float4* a2 = (const float4*)(R2 + (size_t)i2 * 16);
#pragma unroll
    for (int j = 0; j < 4; ++j) {
        const float4 v = a0[j]; const int c = 4 * j;
        acc += fmaxf(fmaf(v.x, sb[c+0], sb[64+c+0]), 0.f) * wsdf[c+0];
        acc += fmaxf(fmaf(v.y, sb[c+1], sb[64+c+1]), 0.f) * wsdf[c+1];
        acc += fmaxf(fmaf(v.z, sb[c+2], sb[64+c+2]), 0.f) * wsdf[c+2];
        acc += fmaxf(fmaf(v.w, sb[c+3], sb[64+c+3]), 0.f) * wsdf[c+3];
    }
#pragma unroll
    for (int j = 0; j < 4; ++j) {
        const float4 v = a1[j]; const int c = 16 + 4 * j;
        acc += fmaxf(fmaf(v.x, sb[c+0], sb[64+c+0]), 0.f) * wsdf[c+0];
        acc += fmaxf(fmaf(v.y, sb[c+1], sb[64+c+1]), 0.f) * wsdf[c+1];
        acc += fmaxf(fmaf(v.z, sb[c+2], sb[64+c+2]), 0.f) * wsdf[c+2];
        acc += fmaxf(fmaf(v.w, sb[c+3], sb[64+c+3]), 0.f) * wsdf[c+3];
    }
#pragma unroll
    for (int j = 0; j < 4; ++j) {
        const float4 v = a2[j]; const int c = 32 + 4 * j;
        acc += fmaxf(fmaf(v.x, sb[c+0], sb[64+c+0]), 0.f) * wsdf[c+0];
        acc += fmaxf(fmaf(v.y, sb[c+1], sb[64+c+1]), 0.f) * wsdf[c+1];
        acc += fmaxf(fmaf(v.z, sb[c+2], sb[64+c+2]), 0.f) * wsdf[c+2];
        acc += fmaxf(fmaf(v.w, sb[c+3], sb[64+c+3]), 0.f) * wsdf[c+3];
    }
    out[n] = acc;
}

// ---------------------------------------------------------------------------
extern "C" void kernel_launch(void* const* d_in, const int* in_sizes, int n_in,
                              void* d_out, int out_size, void* d_ws, size_t ws_size,
                              hipStream_t stream)
{
    const float* feats = (const float*)d_in[0];
    const float* w_p1  = (const float*)d_in[1];
    const float* bn1g  = (const float*)d_in[2];
    const float* bn1b  = (const float*)d_in[3];
    const float* w1    = (const float*)d_in[4];
    const float* bn2g  = (const float*)d_in[5];
    const float* bn2b  = (const float*)d_in[6];
    const float* w2    = (const float*)d_in[7];
    const float* dbng  = (const float*)d_in[8];
    const float* dbnb  = (const float*)d_in[9];
    const float* dw    = (const float*)d_in[10];
    const float* bn3g  = (const float*)d_in[11];
    const float* bn3b  = (const float*)d_in[12];
    const float* wsdf  = (const float*)d_in[13];
    const float* bsdf  = (const float*)d_in[14];
    const int* nbr0    = (const int*)d_in[15];
    const int* nbr1    = (const int*)d_in[16];
    const int* nbr2    = (const int*)d_in[17];
    const int* down01  = (const int*)d_in[18];
    const int* down12  = (const int*)d_in[19];
    const int* p01     = (const int*)d_in[20];
    const int* p12     = (const int*)d_in[21];

    const int N0 = in_sizes[0] / 2;
    const int N1 = in_sizes[18] / 8;   // down01 is [8, N1]
    const int N2 = in_sizes[19] / 8;   // down12 is [8, N2]

    // workspace layout (fp32): A | T | R0 | R1 | R2 | stats(128) | sb(128)
    float* A     = (float*)d_ws;
    float* T     = A  + (size_t)N0 * 16;
    float* R0    = T  + (size_t)N0 * 16;
    float* R1    = R0 + (size_t)N0 * 16;
    float* R2    = R1 + (size_t)N1 * 16;
    float* stats = R2 + (size_t)N2 * 16;
    float* sb    = stats + 128;

    hipMemsetAsync(stats, 0, 128 * sizeof(float), stream);

    const dim3 B(256);
    auto grid  = [](int n) { return dim3((unsigned)((n + 255) / 256)); };
    auto gridv = [](int n) { return dim3((unsigned)((n * 4 + 255) / 256)); };

    // ---- level 0 ----
    sconv_k<27, 2><<<grid(N0), B, 0, stream>>>(feats, nbr0, w_p1, R0, stats, N0, N0, 0);
    fin_k<<<1, 64, 0, stream>>>(stats, bn1g, bn1b, sb, 16, 1.0f / N0);
    apply_k<<<gridv(N0), B, 0, stream>>>(R0, sb, A, N0);
    sconv_k<27, 16><<<grid(N0), B, 0, stream>>>(A, nbr0, w1, T, stats, N0, N0, 0);
    fin_k<<<1, 64, 0, stream>>>(stats, bn2g, bn2b, sb, 16, 1.0f / N0);
    apply_k<<<gridv(N0), B, 0, stream>>>(T, sb, A, N0);
    sconv_k<27, 16><<<grid(N0), B, 0, stream>>>(A, nbr0, w2, R0, stats, N0, N0, 1);
    fin_k<<<1, 64, 0, stream>>>(stats, dbng, dbnb, sb, 16, 1.0f / N0);
    apply_k<<<gridv(N0), B, 0, stream>>>(R0, sb, A, N0);
    sconv_k<8, 16><<<grid(N1), B, 0, stream>>>(A, down01, dw, R1, stats, N1, N0, 0);

    // ---- level 1 ----
    fin_k<<<1, 64, 0, stream>>>(stats, bn1g + 16, bn1b + 16, sb, 16, 1.0f / N1);
    apply_k<<<gridv(N1), B, 0, stream>>>(R1, sb, A, N1);
    sconv_k<27, 16><<<grid(N1), B, 0, stream>>>(A, nbr1, w1 + 6912, T, stats, N1, N1, 0);
    fin_k<<<1, 64, 0, stream>>>(stats, bn2g + 16, bn2b + 16, sb, 16, 1.0f / N1);
    apply_k<<<gridv(N1), B, 0, stream>>>(T, sb, A, N1);
    sconv_k<27, 16><<<grid(N1), B, 0, stream>>>(A, nbr1, w2 + 6912, R1, stats, N1, N1, 1);
    fin_k<<<1, 64, 0, stream>>>(stats, dbng + 16, dbnb + 16, sb, 16, 1.0f / N1);
    apply_k<<<gridv(N1), B, 0, stream>>>(R1, sb, A, N1);
    sconv_k<8, 16><<<grid(N2), B, 0, stream>>>(A, down12, dw + 2048, R2, stats, N2, N1, 0);

    // ---- level 2 ----
    fin_k<<<1, 64, 0, stream>>>(stats, bn1g + 32, bn1b + 32, sb, 16, 1.0f / N2);
    apply_k<<<gridv(N2), B, 0, stream>>>(R2, sb, A, N2);
    sconv_k<27, 16><<<grid(N2), B, 0, stream>>>(A, nbr2, w1 + 2 * 6912, T, stats, N2, N2, 0);
    fin_k<<<1, 64, 0, stream>>>(stats, bn2g + 32, bn2b + 32, sb, 16, 1.0f / N2);
    apply_k<<<gridv(N2), B, 0, stream>>>(T, sb, A, N2);
    sconv_k<27, 16><<<grid(N2), B, 0, stream>>>(A, nbr2, w2 + 2 * 6912, R2, nullptr, N2, N2, 1);

    // ---- final concat + BN48 + ReLU + linear ----
    gstats_k<<<512, B, 0, stream>>>(R0, R1, R2, p01, p12, stats, N0);
    fin_k<<<1, 64, 0, stream>>>(stats, bn3g, bn3b, sb, 48, 1.0f / N0);
    out_k<<<grid(N0), B, 0, stream>>>(R0, R1, R2, p01, p12, sb, wsdf, bsdf,
                                      (float*)d_out, N0);
}

// Round 2
// 886.342 us; speedup vs baseline: 1.0637x; 1.0637x over previous
//
#include <hip/hip_runtime.h>

#define BN_EPS 1e-4f

// ---------------------------------------------------------------------------
// wave-wide (64-lane) butterfly sum
__device__ __forceinline__ float wred(float v) {
#pragma unroll
    for (int off = 32; off > 0; off >>= 1) v += __shfl_xor(v, off);
    return v;
}

// ---------------------------------------------------------------------------
// Fused rulebook gather-conv:
//   A_row = HASBN ? relu(bn(act[idx])) : act[idx]       (BN from stats_in)
//   out[n] = (addSkip ? out[n] : 0) + sum_k A_row(nbr[k,n]) @ W[k]
//   stats_out += per-channel {sum, sumsq} of out        (for the NEXT BN)
// - thread = one output site, 16 fp32 accumulators in VGPRs
// - idx loads batched in chunks of 9 (independent loads -> one vmcnt batch)
// - sentinel (idx == Nin) taps skipped; W is wave-uniform -> scalar loads
template <int K, int CIN, bool HASBN>
__global__ __launch_bounds__(256) void conv_k(
    const float* __restrict__ act,      // [Nin, CIN] (pre-BN)
    const int* __restrict__ nbr,        // [K, Nout], sentinel == Nin
    const float* __restrict__ W,        // [K, CIN, 16]
    const float* __restrict__ g,        // [16] BN gamma (input BN)
    const float* __restrict__ b,        // [16] BN beta
    const float* __restrict__ stats_in, // [128] sums of act (sum | sumsq@64)
    float* __restrict__ out,            // [Nout, 16]
    float* __restrict__ stats_out,      // [128] or nullptr
    int Nout, int Nin, int addSkip, float invN)
{
    // --- BN prologue: per-thread (wave-uniform) scale/bias for input rows ---
    float sc[16], bi[16];
    if constexpr (HASBN) {
#pragma unroll
        for (int c = 0; c < 16; ++c) {
            const float mean = stats_in[c] * invN;
            const float var  = stats_in[64 + c] * invN - mean * mean;
            const float s    = g[c] * rsqrtf(var + BN_EPS);
            sc[c] = s;
            bi[c] = fmaf(-mean, s, b[c]);
        }
    }

    const int n = blockIdx.x * 256 + threadIdx.x;
    const bool valid = (n < Nout);

    float acc[16];
#pragma unroll
    for (int c = 0; c < 16; ++c) acc[c] = 0.f;

    if (valid) {
#pragma unroll
        for (int kk = 0; kk < K; kk += 9) {
            int idxs[9];
#pragma unroll
            for (int j = 0; j < 9; ++j)
                if (kk + j < K) idxs[j] = nbr[(size_t)(kk + j) * Nout + n];
#pragma unroll
            for (int j = 0; j < 9; ++j) {
                if (kk + j >= K) continue;
                const int idx = idxs[j];
                if (idx < Nin) {
                    const float* __restrict__ Wk = W + (kk + j) * (CIN * 16);
                    if constexpr (CIN == 16) {
                        const float4* ar = (const float4*)(act + (size_t)idx * 16);
                        float4 r0 = ar[0], r1 = ar[1], r2 = ar[2], r3 = ar[3];
                        float a[16];
                        a[0] = r0.x; a[1] = r0.y; a[2] = r0.z; a[3] = r0.w;
                        a[4] = r1.x; a[5] = r1.y; a[6] = r1.z; a[7] = r1.w;
                        a[8] = r2.x; a[9] = r2.y; a[10] = r2.z; a[11] = r2.w;
                        a[12] = r3.x; a[13] = r3.y; a[14] = r3.z; a[15] = r3.w;
                        if constexpr (HASBN) {
#pragma unroll
                            for (int c = 0; c < 16; ++c)
                                a[c] = fmaxf(fmaf(a[c], sc[c], bi[c]), 0.f);
                        }
#pragma unroll
                        for (int ci = 0; ci < 16; ++ci) {
                            const float av = a[ci];
#pragma unroll
                            for (int co = 0; co < 16; ++co)
                                acc[co] = fmaf(av, Wk[ci * 16 + co], acc[co]);
                        }
                    } else {  // CIN == 2 (p1 conv from raw feats, no BN)
                        const float2 r = *(const float2*)(act + (size_t)idx * 2);
#pragma unroll
                        for (int co = 0; co < 16; ++co)
                            acc[co] = fmaf(r.x, Wk[co], acc[co]);
#pragma unroll
                        for (int co = 0; co < 16; ++co)
                            acc[co] = fmaf(r.y, Wk[16 + co], acc[co]);
                    }
                }
            }
        }
        if (addSkip) {
            const float4* so = (const float4*)(out + (size_t)n * 16);
            const float4 s0 = so[0], s1 = so[1], s2 = so[2], s3 = so[3];
            acc[0] += s0.x; acc[1] += s0.y; acc[2] += s0.z; acc[3] += s0.w;
            acc[4] += s1.x; acc[5] += s1.y; acc[6] += s1.z; acc[7] += s1.w;
            acc[8] += s2.x; acc[9] += s2.y; acc[10] += s2.z; acc[11] += s2.w;
            acc[12] += s3.x; acc[13] += s3.y; acc[14] += s3.z; acc[15] += s3.w;
        }
        float4* o = (float4*)(out + (size_t)n * 16);
        o[0] = make_float4(acc[0], acc[1], acc[2], acc[3]);
        o[1] = make_float4(acc[4], acc[5], acc[6], acc[7]);
        o[2] = make_float4(acc[8], acc[9], acc[10], acc[11]);
        o[3] = make_float4(acc[12], acc[13], acc[14], acc[15]);
    }

    if (stats_out) {  // uniform branch (kernel arg)
        __shared__ float red[4][32];
        const int wave = threadIdx.x >> 6, lane = threadIdx.x & 63;
#pragma unroll
        for (int c = 0; c < 16; ++c) {
            const float v = valid ? acc[c] : 0.f;
            const float ss = wred(v);
            const float qq = wred(v * v);
            if (lane == 0) { red[wave][c] = ss; red[wave][16 + c] = qq; }
        }
        __syncthreads();
        if (threadIdx.x < 32) {
            const int t = threadIdx.x;
            const float v = red[0][t] + red[1][t] + red[2][t] + red[3][t];
            atomicAdd(stats_out + (t < 16 ? t : 48 + t), v);  // sumsq at 64+
        }
    }
}

// ---------------------------------------------------------------------------
// BN finalize (only for the final 48-channel BN): scale/bias from stats.
__global__ void fin_k(float* __restrict__ stats, const float* __restrict__ g,
                      const float* __restrict__ b, float* __restrict__ sb,
                      int C, float invN)
{
    const int c = threadIdx.x;  // launched with 64 threads
    if (c < C) {
        const float mean = stats[c] * invN;
        const float var = stats[64 + c] * invN - mean * mean;
        const float s = g[c] * rsqrtf(var + BN_EPS);
        sb[c] = s;
        sb[64 + c] = fmaf(-mean, s, b[c]);
    }
}

// ---------------------------------------------------------------------------
// Stats of the gathered concat [r0 | r1[p01] | r2[p12[p01]]] over N0 rows.
__global__ __launch_bounds__(256) void gstats_k(
    const float* __restrict__ R0, const float* __restrict__ R1,
    const float* __restrict__ R2, const int* __restrict__ p01,
    const int* __restrict__ p12, float* __restrict__ stats, int N0)
{
    float s[48], q[48];
#pragma unroll
    for (int c = 0; c < 48; ++c) { s[c] = 0.f; q[c] = 0.f; }

    for (int n = blockIdx.x * blockDim.x + threadIdx.x; n < N0;
         n += gridDim.x * blockDim.x) {
        const int i1 = p01[n];
        const int i2 = p12[i1];
        const float4* a0 = (const float4*)(R0 + (size_t)n * 16);
        const float4* a1 = (const float4*)(R1 + (size_t)i1 * 16);
        const float4* a2 = (const float4*)(R2 + (size_t)i2 * 16);
#pragma unroll
        for (int j = 0; j < 4; ++j) {
            const float4 v = a0[j]; const int c = 4 * j;
            s[c] += v.x; q[c] += v.x * v.x; s[c+1] += v.y; q[c+1] += v.y * v.y;
            s[c+2] += v.z; q[c+2] += v.z * v.z; s[c+3] += v.w; q[c+3] += v.w * v.w;
        }
#pragma unroll
        for (int j = 0; j < 4; ++j) {
            const float4 v = a1[j]; const int c = 16 + 4 * j;
            s[c] += v.x; q[c] += v.x * v.x; s[c+1] += v.y; q[c+1] += v.y * v.y;
            s[c+2] += v.z; q[c+2] += v.z * v.z; s[c+3] += v.w; q[c+3] += v.w * v.w;
        }
#pragma unroll
        for (int j = 0; j < 4; ++j) {
            const float4 v = a2[j]; const int c = 32 + 4 * j;
            s[c] += v.x; q[c] += v.x * v.x; s[c+1] += v.y; q[c+1] += v.y * v.y;
            s[c+2] += v.z; q[c+2] += v.z * v.z; s[c+3] += v.w; q[c+3] += v.w * v.w;
        }
    }

    __shared__ float red[4][96];
    const int wave = threadIdx.x >> 6, lane = threadIdx.x & 63;
#pragma unroll
    for (int c = 0; c < 48; ++c) {
        const float ss = wred(s[c]);
        const float qq = wred(q[c]);
        if (lane == 0) { red[wave][c] = ss; red[wave][48 + c] = qq; }
    }
    __syncthreads();
    const int t = threadIdx.x;
    if (t < 96) {
        const float v = red[0][t] + red[1][t] + red[2][t] + red[3][t];
        atomicAdd(stats + (t < 48 ? t : 64 + (t - 48)), v);
    }
}

// ---------------------------------------------------------------------------
// Final: out[n] = relu(bn48(concat)) . w_sdf + b_sdf
__global__ __launch_bounds__(256) void out_k(
    const float* __restrict__ R0, const float* __restrict__ R1,
    const float* __restrict__ R2, const int* __restrict__ p01,
    const int* __restrict__ p12, const float* __restrict__ sb,
    const float* __restrict__ wsdf, const float* __restrict__ bsdf,
    float* __restrict__ out, int N0)
{
    const int n = blockIdx.x * 256 + threadIdx.x;
    if (n >= N0) return;
    const int i1 = p01[n];
    const int i2 = p12[i1];
    float acc = bsdf[0];
    const float4* a0 = (const float4*)(R0 + (size_t)n * 16);
    const float4* a1 = (const float4*)(R1 + (size_t)i1 * 16);
    const float4* a2 = (const float4*)(R2 + (size_t)i2 * 16);
#pragma unroll
    for (int j = 0; j < 4; ++j) {
        const float4 v = a0[j]; const int c = 4 * j;
        acc += fmaxf(fmaf(v.x, sb[c+0], sb[64+c+0]), 0.f) * wsdf[c+0];
        acc += fmaxf(fmaf(v.y, sb[c+1], sb[64+c+1]), 0.f) * wsdf[c+1];
        acc += fmaxf(fmaf(v.z, sb[c+2], sb[64+c+2]), 0.f) * wsdf[c+2];
        acc += fmaxf(fmaf(v.w, sb[c+3], sb[64+c+3]), 0.f) * wsdf[c+3];
    }
#pragma unroll
    for (int j = 0; j < 4; ++j) {
        const float4 v = a1[j]; const int c = 16 + 4 * j;
        acc += fmaxf(fmaf(v.x, sb[c+0], sb[64+c+0]), 0.f) * wsdf[c+0];
        acc += fmaxf(fmaf(v.y, sb[c+1], sb[64+c+1]), 0.f) * wsdf[c+1];
        acc += fmaxf(fmaf(v.z, sb[c+2], sb[64+c+2]), 0.f) * wsdf[c+2];
        acc += fmaxf(fmaf(v.w, sb[c+3], sb[64+c+3]), 0.f) * wsdf[c+3];
    }
#pragma unroll
    for (int j = 0; j < 4; ++j) {
        const float4 v = a2[j]; const int c = 32 + 4 * j;
        acc += fmaxf(fmaf(v.x, sb[c+0], sb[64+c+0]), 0.f) * wsdf[c+0];
        acc += fmaxf(fmaf(v.y, sb[c+1], sb[64+c+1]), 0.f) * wsdf[c+1];
        acc += fmaxf(fmaf(v.z, sb[c+2], sb[64+c+2]), 0.f) * wsdf[c+2];
        acc += fmaxf(fmaf(v.w, sb[c+3], sb[64+c+3]), 0.f) * wsdf[c+3];
    }
    out[n] = acc;
}

// ---------------------------------------------------------------------------
extern "C" void kernel_launch(void* const* d_in, const int* in_sizes, int n_in,
                              void* d_out, int out_size, void* d_ws, size_t ws_size,
                              hipStream_t stream)
{
    const float* feats = (const float*)d_in[0];
    const float* w_p1  = (const float*)d_in[1];
    const float* bn1g  = (const float*)d_in[2];
    const float* bn1b  = (const float*)d_in[3];
    const float* w1    = (const float*)d_in[4];
    const float* bn2g  = (const float*)d_in[5];
    const float* bn2b  = (const float*)d_in[6];
    const float* w2    = (const float*)d_in[7];
    const float* dbng  = (const float*)d_in[8];
    const float* dbnb  = (const float*)d_in[9];
    const float* dw    = (const float*)d_in[10];
    const float* bn3g  = (const float*)d_in[11];
    const float* bn3b  = (const float*)d_in[12];
    const float* wsdf  = (const float*)d_in[13];
    const float* bsdf  = (const float*)d_in[14];
    const int* nbr0    = (const int*)d_in[15];
    const int* nbr1    = (const int*)d_in[16];
    const int* nbr2    = (const int*)d_in[17];
    const int* down01  = (const int*)d_in[18];
    const int* down12  = (const int*)d_in[19];
    const int* p01     = (const int*)d_in[20];
    const int* p12     = (const int*)d_in[21];

    const int N0 = in_sizes[0] / 2;
    const int N1 = in_sizes[18] / 8;   // down01 is [8, N1]
    const int N2 = in_sizes[19] / 8;   // down12 is [8, N2]

    // workspace layout (fp32): T | R0 | R1 | R2 | stats[9][128] | sb(128)
    float* T     = (float*)d_ws;
    float* R0    = T  + (size_t)N0 * 16;
    float* R1    = R0 + (size_t)N0 * 16;
    float* R2    = R1 + (size_t)N1 * 16;
    float* st    = R2 + (size_t)N2 * 16;   // 9 stats buffers of 128 floats
    float* sb    = st + 9 * 128;

    hipMemsetAsync(st, 0, 9 * 128 * sizeof(float), stream);

    const dim3 B(256);
    auto grid = [](int n) { return dim3((unsigned)((n + 255) / 256)); };
    const float i0 = 1.0f / N0, i1 = 1.0f / N1, i2 = 1.0f / N2;
    auto S = [&](int i) { return st + i * 128; };

    // ---- level 0 ----
    conv_k<27, 2, false><<<grid(N0), B, 0, stream>>>(
        feats, nbr0, w_p1, nullptr, nullptr, nullptr, R0, S(0), N0, N0, 0, 0.f);
    conv_k<27, 16, true><<<grid(N0), B, 0, stream>>>(
        R0, nbr0, w1, bn1g, bn1b, S(0), T, S(1), N0, N0, 0, i0);
    conv_k<27, 16, true><<<grid(N0), B, 0, stream>>>(
        T, nbr0, w2, bn2g, bn2b, S(1), R0, S(2), N0, N0, 1, i0);
    conv_k<8, 16, true><<<grid(N1), B, 0, stream>>>(
        R0, down01, dw, dbng, dbnb, S(2), R1, S(3), N1, N0, 0, i0);

    // ---- level 1 ----
    conv_k<27, 16, true><<<grid(N1), B, 0, stream>>>(
        R1, nbr1, w1 + 6912, bn1g + 16, bn1b + 16, S(3), T, S(4), N1, N1, 0, i1);
    conv_k<27, 16, true><<<grid(N1), B, 0, stream>>>(
        T, nbr1, w2 + 6912, bn2g + 16, bn2b + 16, S(4), R1, S(5), N1, N1, 1, i1);
    conv_k<8, 16, true><<<grid(N2), B, 0, stream>>>(
        R1, down12, dw + 2048, dbng + 16, dbnb + 16, S(5), R2, S(6), N2, N1, 0, i1);

    // ---- level 2 ----
    conv_k<27, 16, true><<<grid(N2), B, 0, stream>>>(
        R2, nbr2, w1 + 2 * 6912, bn1g + 32, bn1b + 32, S(6), T, S(7), N2, N2, 0, i2);
    conv_k<27, 16, true><<<grid(N2), B, 0, stream>>>(
        T, nbr2, w2 + 2 * 6912, bn2g + 32, bn2b + 32, S(7), R2, nullptr, N2, N2, 1, i2);

    // ---- final concat + BN48 + ReLU + linear ----
    gstats_k<<<512, B, 0, stream>>>(R0, R1, R2, p01, p12, S(8), N0);
    fin_k<<<1, 64, 0, stream>>>(S(8), bn3g, bn3b, sb, 48, i0);
    out_k<<<grid(N0), B, 0, stream>>>(R0, R1, R2, p01, p12, sb, wsdf, bsdf,
                                      (float*)d_out, N0);
}